// Round 16
// baseline (128.948 us; speedup 1.0000x reference)
//
#include <hip/hip_runtime.h>
#include <hip/hip_bf16.h>

#define NB  4
#define NC  256
#define NC8 32
#define NHW 4096
#define LOG2E 1.4426950408889634f

typedef __attribute__((ext_vector_type(8))) short bf16x8;
typedef __attribute__((ext_vector_type(4))) float f32x4;
typedef __attribute__((ext_vector_type(16))) float f32x16;
typedef __attribute__((ext_vector_type(2))) unsigned u32x2;

__device__ __forceinline__ float ex2(float x) { return __builtin_amdgcn_exp2f(x); }

__device__ __forceinline__ unsigned short f2bf(float f) {
    union { float f; unsigned u; } v; v.f = f;
    unsigned r = v.u + 0x7fffu + ((v.u >> 16) & 1u);
    return (unsigned short)(r >> 16);
}

__device__ __forceinline__ unsigned packbf2(float lo, float hi) {
    __hip_bfloat162 h = __float22bfloat162_rn(make_float2(lo, hi));
    union { __hip_bfloat162 h; unsigned u; } cv; cv.h = h; return cv.u;
}

// ---------------- proj: FUSED qk (fp32 VALU) + v (bf16 MFMA GEMM) ------------
// blocks [0,1024): v-body (unchanged r14 double-buffered GEMM, pre-transposed
// vt out, XCD swizzle). blocks [1024,1536): qk-body, 4 og x 64-c slices so the
// block is uniformly 256 threads and LDS unions at 34KB (same 16 waves/CU for
// both parts). Fusing overlaps the VALU-bound qk work with the MFMA/mem-bound
// v work and removes one kernel-launch gap.
__global__ __launch_bounds__(256) void proj(
    const float* __restrict__ x, const float* __restrict__ g,
    const float* __restrict__ qw, const float* __restrict__ qb,
    const float* __restrict__ kw, const float* __restrict__ kb,
    const float* __restrict__ vw, const float* __restrict__ vb,
    unsigned short* __restrict__ qt, unsigned short* __restrict__ kt,
    unsigned short* __restrict__ vt)
{
    __shared__ alignas(16) char fsm[34048];
    const int tid = threadIdx.x;

    if (blockIdx.x < 1024) {
        // ---------------- v-body (byte-identical logic to r14/r15) ----------
        unsigned short (*WsL)[264]      = (unsigned short(*)[264])fsm;
        unsigned short (*InL)[128][32]  = (unsigned short(*)[128][32])(fsm + 16896);

        const int id  = blockIdx.x;
        const int y   = id >> 7;
        const int r_  = id & 127;
        const int b   = r_ >> 5;
        const int pt  = r_ & 31;
        const int row0 = y * 32;
        const int wv  = tid >> 6;
        const int lane = tid & 63;
        const int l16 = lane & 15;
        const int g4  = lane >> 4;
        const int px0 = pt * 128;

        {
            const int wrow = tid >> 3;
            const int wcb  = (tid & 7) * 32;
            const float* wsrc = vw + (size_t)(row0 + wrow) * NC + wcb;
#pragma unroll
            for (int q = 0; q < 4; ++q) {
                f32x4 a  = *(const f32x4*)(wsrc + q * 8);
                f32x4 b2 = *(const f32x4*)(wsrc + q * 8 + 4);
                union { unsigned u[4]; bf16x8 v; } pk8;
                pk8.u[0] = packbf2(a[0],  a[1]);  pk8.u[1] = packbf2(a[2],  a[3]);
                pk8.u[2] = packbf2(b2[0], b2[1]); pk8.u[3] = packbf2(b2[2], b2[3]);
                *(bf16x8*)&WsL[wrow][wcb + q * 8] = pk8.v;
            }
        }

        const int spx = tid & 127;
        const int sch = (tid >> 7) * 16;
        const float* gb = g + (size_t)b * NC * NHW + px0 + spx;

        auto ldregs = [&](int c0, float pv[2][8]) {
#pragma unroll
            for (int j = 0; j < 2; ++j)
#pragma unroll
                for (int q = 0; q < 8; ++q)
                    pv[j][q] = gb[(size_t)(c0 + sch + j * 8 + q) * NHW];
        };
        auto wrlds = [&](int buf, float pv[2][8]) {
#pragma unroll
            for (int j = 0; j < 2; ++j) {
                union { unsigned u[4]; bf16x8 v; } pk8;
                pk8.u[0] = packbf2(pv[j][0], pv[j][1]); pk8.u[1] = packbf2(pv[j][2], pv[j][3]);
                pk8.u[2] = packbf2(pv[j][4], pv[j][5]); pk8.u[3] = packbf2(pv[j][6], pv[j][7]);
                *(bf16x8*)&InL[buf][spx][sch + j * 8] = pk8.v;
            }
        };

        f32x4 z = {0.f, 0.f, 0.f, 0.f};
        f32x4 acc[2][2] = {{z, z}, {z, z}};

        float pv[2][8];
        ldregs(0, pv);
        wrlds(0, pv);
        __syncthreads();

        int buf = 0;
        for (int c0 = 0; c0 < NC; c0 += 32) {
            if (c0 + 32 < NC) ldregs(c0 + 32, pv);

            bf16x8 af0 = *(const bf16x8*)&WsL[l16][c0 + g4 * 8];
            bf16x8 af1 = *(const bf16x8*)&WsL[16 + l16][c0 + g4 * 8];
#pragma unroll
            for (int ntl = 0; ntl < 2; ++ntl) {
                const int nt = wv * 2 + ntl;
                bf16x8 bfg = *(const bf16x8*)&InL[buf][nt * 16 + l16][g4 * 8];
                acc[0][ntl] = __builtin_amdgcn_mfma_f32_16x16x32_bf16(af0, bfg, acc[0][ntl], 0, 0, 0);
                acc[1][ntl] = __builtin_amdgcn_mfma_f32_16x16x32_bf16(af1, bfg, acc[1][ntl], 0, 0, 0);
            }

            if (c0 + 32 < NC) {
                wrlds(buf ^ 1, pv);
                __syncthreads();
                buf ^= 1;
            }
        }

#pragma unroll
        for (int rt = 0; rt < 2; ++rt) {
            f32x4 b4 = *(const f32x4*)(vb + row0 + rt * 16 + g4 * 4);
#pragma unroll
            for (int ntl = 0; ntl < 2; ++ntl) {
                const int n  = px0 + (wv * 2 + ntl) * 16 + l16;
                const int mg = n >> 3, mo = n & 7;
#pragma unroll
                for (int r = 0; r < 4; ++r) {
                    const int c = row0 + rt * 16 + g4 * 4 + r;
                    vt[(((size_t)b * (NHW / 8) + mg) * NC + c) * 8 + mo] =
                        f2bf(acc[rt][ntl][r] + b4[r]);
                }
            }
        }
    } else {
        // ---------------- qk-body: fp32 VALU, 4 og x 64-c slices ------------
        float (*pl)[64][33] = (float(*)[64][33])fsm;   // [og][px][o] +1 pad

        const int fid = blockIdx.x - 1024;   // 0..511
        const int y   = fid >> 8;
        const int rst = fid & 255;
        const int b   = rst >> 6;
        const int nt  = rst & 63;
        const int px  = tid & 63;
        const int og  = tid >> 6;            // 0..3: c-slice og*64..+64
        const int n   = nt * 64 + px;

        const float* in   = y ? g  : x;
        const float* W    = y ? kw : qw;
        const float* bias = y ? kb : qb;
        unsigned short* dst = y ? kt : qt;

        const float* ip = in + (size_t)b * NC * NHW + n;
        const int c0 = og * 64;

        float a[32];
#pragma unroll
        for (int o = 0; o < 32; ++o) a[o] = 0.f;

        for (int cl = 0; cl < 64; cl += 4) {
            const int c = c0 + cl;
            float v0 = ip[(size_t)(c+0)*NHW], v1 = ip[(size_t)(c+1)*NHW];
            float v2 = ip[(size_t)(c+2)*NHW], v3 = ip[(size_t)(c+3)*NHW];
#pragma unroll
            for (int o = 0; o < 32; ++o) {
                f32x4 w = *(const f32x4*)(W + (size_t)o * NC + c);
                a[o] = fmaf(w[0], v0, a[o]); a[o] = fmaf(w[1], v1, a[o]);
                a[o] = fmaf(w[2], v2, a[o]); a[o] = fmaf(w[3], v3, a[o]);
            }
        }
#pragma unroll
        for (int o = 0; o < 32; ++o) pl[og][px][o] = a[o];
        __syncthreads();

        // combine: thread (px, og) owns outputs og*8 .. og*8+7
        float s8[8];
#pragma unroll
        for (int j = 0; j < 8; ++j) {
            float s = 0.f;
#pragma unroll
            for (int gg = 0; gg < 4; ++gg) s += pl[gg][px][og * 8 + j];
            s8[j] = s + bias[og * 8 + j];
        }
        const float scl = y ? 1.0f : LOG2E;   // q pre-scaled for exp2 softmax
        u32x2 pk0, pk1;
        pk0[0] = packbf2(s8[0] * scl, s8[1] * scl);
        pk0[1] = packbf2(s8[2] * scl, s8[3] * scl);
        pk1[0] = packbf2(s8[4] * scl, s8[5] * scl);
        pk1[1] = packbf2(s8[6] * scl, s8[7] * scl);
        unsigned short* dp = dst + ((size_t)b * NHW + n) * NC8 + og * 8;
        *(u32x2*)dp       = pk0;
        *(u32x2*)(dp + 4) = pk1;
    }
}

// ---------------- attn: r15 structure + incremental stream pointers ----------
// V/K bases are per-thread constants advanced by fixed strides (2 scalar adds
// per reload) instead of full 64-bit recompute from t (~40-50 VALU/wave/step).
// Profile said ~70% issue-busy -> shave issued instructions.
__global__ __launch_bounds__(512, 2) void attn(
    const unsigned short* __restrict__ qt, const unsigned short* __restrict__ kt,
    const unsigned short* __restrict__ vt, const float* __restrict__ x,
    const float* __restrict__ gamma, float* __restrict__ out)
{
    const int b   = blockIdx.x & 3;          // XCD swizzle (r12-proven)
    const int nt  = blockIdx.x >> 2;
    const int tid = threadIdx.x;
    const int wv  = tid >> 6;                // 0..7
    const int rg  = (wv >> 2) & 1;           // row-group (32 rows)
    const int cg  = (wv >> 1) & 1;           // c-half (128 ch)
    const int s   = wv & 1;                  // key-half (2048 keys)
    const int lane = tid & 63;
    const int c32 = lane & 31;
    const int hi  = lane >> 5;

    __shared__ alignas(16) char smem[66048];
    float* obuf = (float*)smem;              // 64KB combine buffer
    float* ml   = (float*)(smem + 65536);    // [rg][s][32]

    const unsigned short* ktb = kt + (size_t)b * NHW * NC8;
    const unsigned short* vtb = vt + (size_t)b * (NHW / 8) * NC * 8;

    const int nr0 = nt * 64 + rg * 32;
    const unsigned short* qp = qt + ((size_t)b * NHW + nr0 + c32) * NC8;
    const bf16x8 qf0 = *(const bf16x8*)(qp + hi * 8);        // d 0..15
    const bf16x8 qf1 = *(const bf16x8*)(qp + 16 + hi * 8);   // d 16..31

    f32x16 acc[4];
#pragma unroll
    for (int ct = 0; ct < 4; ++ct) acc[ct] = (f32x16)0.0f;
    float lrun = 0.f;
    const f32x16 zz = (f32x16)0.0f;

    // per-thread constant V offsets (elements): ((kc*2+hi)*NC + cg*128+ct*32+c32)*8
    int voff[8];
#pragma unroll
    for (int kc = 0; kc < 2; ++kc)
#pragma unroll
        for (int ct = 0; ct < 4; ++ct)
            voff[kc * 4 + ct] = (((kc * 2 + hi) * NC) + cg * 128 + ct * 32 + c32) * 8;

    const size_t VSTEP = (size_t)4 * NC * 8;     // one 32-key step of vt
    const size_t KSTEP = (size_t)32 * NC8;       // one 32-key step of kt

    // stream pointers (advanced incrementally; strides are compile-time consts)
    const unsigned short* vApt = vtb + (size_t)(s * 256) * NC * 8;   // t = 0,2,4,..
    const unsigned short* vBpt = vApt + VSTEP;                        // t = 1,3,5,..
    const unsigned short* kApt = ktb + (size_t)(s * 2048 + c32) * NC8 + hi * 8;
    const unsigned short* kBpt = kApt + KSTEP;

    auto loadV = [&](bf16x8* v, const unsigned short* p) {
#pragma unroll
        for (int i = 0; i < 8; ++i)
            v[i] = *(const bf16x8*)(p + voff[i]);
    };
    auto loadK = [&](bf16x8& ka, bf16x8& kb, const unsigned short* p) {
        ka = *(const bf16x8*)p;
        kb = *(const bf16x8*)(p + 16);
    };
    auto qkt_pack = [&](const bf16x8& kfa, const bf16x8& kfb, unsigned* w) {
        f32x16 e = __builtin_amdgcn_mfma_f32_32x32x16_bf16(kfa, qf0, zz, 0, 0, 0);
        e = __builtin_amdgcn_mfma_f32_32x32x16_bf16(kfb, qf1, e, 0, 0, 0);
        float ladd = 0.f;
#pragma unroll
        for (int q = 0; q < 8; ++q) {
            const float pa = ex2(e[2 * q]);
            const float pb = ex2(e[2 * q + 1]);
            ladd += pa + pb;
            w[q] = packbf2(pa, pb);
        }
        lrun += ladd;
    };
    auto pv = [&](const bf16x8* v, const unsigned* w) {
#pragma unroll
        for (int kc = 0; kc < 2; ++kc) {
            const unsigned q0 = w[kc * 4 + 0];
            const unsigned q1 = w[kc * 4 + 1];
            const unsigned q2 = w[kc * 4 + 2];
            const unsigned q3 = w[kc * 4 + 3];
            const unsigned q0x = (unsigned)__shfl_xor((int)q0, 32);
            const unsigned q1x = (unsigned)__shfl_xor((int)q1, 32);
            const unsigned q2x = (unsigned)__shfl_xor((int)q2, 32);
            const unsigned q3x = (unsigned)__shfl_xor((int)q3, 32);
            union { unsigned u[4]; bf16x8 vv; } pa;
            pa.u[0] = hi ? q2x : q0;
            pa.u[1] = hi ? q3x : q1;
            pa.u[2] = hi ? q2  : q0x;
            pa.u[3] = hi ? q3  : q1x;
#pragma unroll
            for (int ct = 0; ct < 4; ++ct)
                acc[ct] = __builtin_amdgcn_mfma_f32_32x32x16_bf16(pa.vv, v[kc * 4 + ct], acc[ct], 0, 0, 0);
        }
    };

    // ---- pipeline: V/K 2-deep, softmax two ahead (wA even / wB odd) ----
    bf16x8 vA[8], vB[8], kAa, kAb, kBa, kBb;
    unsigned wA[8], wB[8];

    loadV(vA, vApt); loadK(kAa, kAb, kApt);
    loadV(vB, vBpt); loadK(kBa, kBb, kBpt);
    qkt_pack(kAa, kAb, wA);                  // w(0)
    kApt += 2 * KSTEP; loadK(kAa, kAb, kApt);        // K(2)
    qkt_pack(kBa, kBb, wB);                  // w(1)
    kBpt += 2 * KSTEP; loadK(kBa, kBb, kBpt);        // K(3)

    for (int tt = 0; tt < 32; ++tt) {
        const int t = tt * 2;
        pv(vA, wA);                          // consume w(t), vA(t)
        if (t + 2 < 64) {
            qkt_pack(kAa, kAb, wA);          // produce w(t+2)
            vApt += 2 * VSTEP; loadV(vA, vApt);              // V(t+2)
            if (t + 4 < 64) { kApt += 2 * KSTEP; loadK(kAa, kAb, kApt); }  // K(t+4)
        }
        pv(vB, wB);                          // consume w(t+1), vB(t+1)
        if (t + 3 < 64) {
            qkt_pack(kBa, kBb, wB);          // produce w(t+3)
            vBpt += 2 * VSTEP; loadV(vB, vBpt);              // V(t+3)
            if (t + 5 < 64) { kBpt += 2 * KSTEP; loadK(kBa, kBb, kBpt); }  // K(t+5)
        }
    }

    // ---- 2-way s-combine ----
    lrun += __shfl_xor(lrun, 32);
    ml[(rg * 2 + s) * 32 + c32] = lrun;
    __syncthreads();
    const float L = ml[(rg * 2 + 0) * 32 + c32] + ml[(rg * 2 + 1) * 32 + c32];
    const float gil = gamma[0] / L;
    float il[16];
#pragma unroll
    for (int r = 0; r < 16; ++r)
        il[r] = __shfl(gil, (r & 3) + 8 * (r >> 2) + 4 * hi);

    if (s == 1) {
#pragma unroll
        for (int ct = 0; ct < 4; ++ct)
#pragma unroll
            for (int rq = 0; rq < 4; ++rq) {
                f32x4 v;
#pragma unroll
                for (int j = 0; j < 4; ++j) v[j] = acc[ct][rq * 4 + j];
                *(f32x4*)(obuf + ((((rg * 2 + cg) * 16 + ct * 4 + rq) * 64) + lane) * 4) = v;
            }
    }
    __syncthreads();
    if (s == 0) {
#pragma unroll
        for (int ct = 0; ct < 4; ++ct) {
            const int c = cg * 128 + ct * 32 + c32;
#pragma unroll
            for (int rq = 0; rq < 4; ++rq) {
                const f32x4 p = *(const f32x4*)(obuf + ((((rg * 2 + cg) * 16 + ct * 4 + rq) * 64) + lane) * 4);
                const int nglob = nt * 64 + rg * 32 + rq * 8 + hi * 4;
                const size_t o = ((size_t)b * NC + c) * NHW + nglob;
                const f32x4 xv = *(const f32x4*)(x + o);
                f32x4 res;
#pragma unroll
                for (int j = 0; j < 4; ++j) {
                    const float v = acc[ct][rq * 4 + j] + p[j];
                    res[j] = fmaf(v, il[rq * 4 + j], xv[j]);
                }
                *(f32x4*)(out + o) = res;
            }
        }
    }
}

extern "C" void kernel_launch(void* const* d_in, const int* in_sizes, int n_in,
                              void* d_out, int out_size, void* d_ws, size_t ws_size,
                              hipStream_t stream) {
    const float* x     = (const float*)d_in[0];
    const float* g     = (const float*)d_in[1];
    const float* qw    = (const float*)d_in[2];
    const float* qb    = (const float*)d_in[3];
    const float* kw    = (const float*)d_in[4];
    const float* kb    = (const float*)d_in[5];
    const float* vw    = (const float*)d_in[6];
    const float* vb    = (const float*)d_in[7];
    const float* gamma = (const float*)d_in[8];
    float* out = (float*)d_out;

    unsigned short* qt = (unsigned short*)d_ws;
    unsigned short* kt = qt + (size_t)NB * NHW * NC8;
    unsigned short* vt = kt + (size_t)NB * NHW * NC8;

    proj<<<1536, 256, 0, stream>>>(x, g, qw, qb, kw, kb, vw, vb, qt, kt, vt);
    attn<<<NB * (NHW / 64), 512, 0, stream>>>(qt, kt, vt, x, gamma, out);
}

// Round 17
// 117.729 us; speedup vs baseline: 1.0953x; 1.0953x over previous
//
#include <hip/hip_runtime.h>
#include <hip/hip_bf16.h>

#define NB  4
#define NC  256
#define NC8 32
#define NHW 4096
#define LOG2E 1.4426950408889634f

typedef __attribute__((ext_vector_type(8))) short bf16x8;
typedef __attribute__((ext_vector_type(4))) float f32x4;
typedef __attribute__((ext_vector_type(16))) float f32x16;
typedef __attribute__((ext_vector_type(2))) unsigned u32x2;

__device__ __forceinline__ float ex2(float x) { return __builtin_amdgcn_exp2f(x); }

__device__ __forceinline__ unsigned short f2bf(float f) {
    union { float f; unsigned u; } v; v.f = f;
    unsigned r = v.u + 0x7fffu + ((v.u >> 16) & 1u);
    return (unsigned short)(r >> 16);
}

__device__ __forceinline__ unsigned packbf2(float lo, float hi) {
    __hip_bfloat162 h = __float22bfloat162_rn(make_float2(lo, hi));
    union { __hip_bfloat162 h; unsigned u; } cv; cv.h = h; return cv.u;
}

// ---------------- qk_proj: fp32 VALU, c-split og (r15-proven) ----------------
__global__ __launch_bounds__(512) void qk_proj(
    const float* __restrict__ x, const float* __restrict__ g,
    const float* __restrict__ qw, const float* __restrict__ qb,
    const float* __restrict__ kw, const float* __restrict__ kb,
    unsigned short* __restrict__ qt, unsigned short* __restrict__ kt)
{
    const int b  = blockIdx.x >> 6;
    const int nt = blockIdx.x & 63;
    const int y  = blockIdx.y;
    const int px = threadIdx.x & 63;
    const int og = threadIdx.x >> 6;
    const int n  = nt * 64 + px;

    const float* in   = y ? g  : x;
    const float* W    = y ? kw : qw;
    const float* bias = y ? kb : qb;
    unsigned short* dst = y ? kt : qt;

    __shared__ float pl[8][64][33];

    const float* ip = in + (size_t)b * NC * NHW + n;
    const int c0 = og * 32;

    float a[32];
#pragma unroll
    for (int o = 0; o < 32; ++o) a[o] = 0.f;

    for (int cl = 0; cl < 32; cl += 4) {
        const int c = c0 + cl;
        float v0 = ip[(size_t)(c+0)*NHW], v1 = ip[(size_t)(c+1)*NHW];
        float v2 = ip[(size_t)(c+2)*NHW], v3 = ip[(size_t)(c+3)*NHW];
#pragma unroll
        for (int o = 0; o < 32; ++o) {
            f32x4 w = *(const f32x4*)(W + (size_t)o * NC + c);
            a[o] = fmaf(w[0], v0, a[o]); a[o] = fmaf(w[1], v1, a[o]);
            a[o] = fmaf(w[2], v2, a[o]); a[o] = fmaf(w[3], v3, a[o]);
        }
    }
#pragma unroll
    for (int o = 0; o < 32; ++o) pl[og][px][o] = a[o];
    __syncthreads();

    float s4[4];
#pragma unroll
    for (int j = 0; j < 4; ++j) {
        float s = 0.f;
#pragma unroll
        for (int gg = 0; gg < 8; ++gg) s += pl[gg][px][og * 4 + j];
        s4[j] = s + bias[og * 4 + j];
    }
    const float scl = y ? 1.0f : LOG2E;
    u32x2 pk;
    pk[0] = packbf2(s4[0] * scl, s4[1] * scl);
    pk[1] = packbf2(s4[2] * scl, s4[3] * scl);
    *(u32x2*)(dst + ((size_t)b * NHW + n) * NC8 + og * 4) = pk;
}

// ---------------- v_proj: bf16 MFMA GEMM, pre-transposed out (r14-proven) ----
__global__ __launch_bounds__(256) void v_proj(
    const float* __restrict__ g, const float* __restrict__ vw,
    const float* __restrict__ vb, unsigned short* __restrict__ vt)
{
    const int id  = blockIdx.x;
    const int y   = id >> 7;
    const int r_  = id & 127;
    const int b   = r_ >> 5;
    const int pt  = r_ & 31;
    const int row0 = y * 32;
    const int tid = threadIdx.x;
    const int wv  = tid >> 6;
    const int lane = tid & 63;
    const int l16 = lane & 15;
    const int g4  = lane >> 4;
    const int px0 = pt * 128;

    __shared__ alignas(16) unsigned short WsL[32][264];
    __shared__ alignas(16) unsigned short InL[2][128][32];

    {
        const int wrow = tid >> 3;
        const int wcb  = (tid & 7) * 32;
        const float* wsrc = vw + (size_t)(row0 + wrow) * NC + wcb;
#pragma unroll
        for (int q = 0; q < 4; ++q) {
            f32x4 a  = *(const f32x4*)(wsrc + q * 8);
            f32x4 b2 = *(const f32x4*)(wsrc + q * 8 + 4);
            union { unsigned u[4]; bf16x8 v; } pk8;
            pk8.u[0] = packbf2(a[0],  a[1]);  pk8.u[1] = packbf2(a[2],  a[3]);
            pk8.u[2] = packbf2(b2[0], b2[1]); pk8.u[3] = packbf2(b2[2], b2[3]);
            *(bf16x8*)&WsL[wrow][wcb + q * 8] = pk8.v;
        }
    }

    const int spx = tid & 127;
    const int sch = (tid >> 7) * 16;
    const float* gb = g + (size_t)b * NC * NHW + px0 + spx;

    auto ldregs = [&](int c0, float pv[2][8]) {
#pragma unroll
        for (int j = 0; j < 2; ++j)
#pragma unroll
            for (int q = 0; q < 8; ++q)
                pv[j][q] = gb[(size_t)(c0 + sch + j * 8 + q) * NHW];
    };
    auto wrlds = [&](int buf, float pv[2][8]) {
#pragma unroll
        for (int j = 0; j < 2; ++j) {
            union { unsigned u[4]; bf16x8 v; } pk8;
            pk8.u[0] = packbf2(pv[j][0], pv[j][1]); pk8.u[1] = packbf2(pv[j][2], pv[j][3]);
            pk8.u[2] = packbf2(pv[j][4], pv[j][5]); pk8.u[3] = packbf2(pv[j][6], pv[j][7]);
            *(bf16x8*)&InL[buf][spx][sch + j * 8] = pk8.v;
        }
    };

    f32x4 z = {0.f, 0.f, 0.f, 0.f};
    f32x4 acc[2][2] = {{z, z}, {z, z}};

    float pv[2][8];
    ldregs(0, pv);
    wrlds(0, pv);
    __syncthreads();

    int buf = 0;
    for (int c0 = 0; c0 < NC; c0 += 32) {
        if (c0 + 32 < NC) ldregs(c0 + 32, pv);

        bf16x8 af0 = *(const bf16x8*)&WsL[l16][c0 + g4 * 8];
        bf16x8 af1 = *(const bf16x8*)&WsL[16 + l16][c0 + g4 * 8];
#pragma unroll
        for (int ntl = 0; ntl < 2; ++ntl) {
            const int nt = wv * 2 + ntl;
            bf16x8 bfg = *(const bf16x8*)&InL[buf][nt * 16 + l16][g4 * 8];
            acc[0][ntl] = __builtin_amdgcn_mfma_f32_16x16x32_bf16(af0, bfg, acc[0][ntl], 0, 0, 0);
            acc[1][ntl] = __builtin_amdgcn_mfma_f32_16x16x32_bf16(af1, bfg, acc[1][ntl], 0, 0, 0);
        }

        if (c0 + 32 < NC) {
            wrlds(buf ^ 1, pv);
            __syncthreads();
            buf ^= 1;
        }
    }

#pragma unroll
    for (int rt = 0; rt < 2; ++rt) {
        f32x4 b4 = *(const f32x4*)(vb + row0 + rt * 16 + g4 * 4);
#pragma unroll
        for (int ntl = 0; ntl < 2; ++ntl) {
            const int n  = px0 + (wv * 2 + ntl) * 16 + l16;
            const int mg = n >> 3, mo = n & 7;
#pragma unroll
            for (int r = 0; r < 4; ++r) {
                const int c = row0 + rt * 16 + g4 * 4 + r;
                vt[(((size_t)b * (NHW / 8) + mg) * NC + c) * 8 + mo] =
                    f2bf(acc[rt][ntl][r] + b4[r]);
            }
        }
    }
}

// ---------------- attn: r16 structure (incremental stream pointers) ----------
// UNCHANGED from r16 — the pointer optimization cut attn to ~39us; this round
// just un-confounds it from the failed proj fusion.
__global__ __launch_bounds__(512, 2) void attn(
    const unsigned short* __restrict__ qt, const unsigned short* __restrict__ kt,
    const unsigned short* __restrict__ vt, const float* __restrict__ x,
    const float* __restrict__ gamma, float* __restrict__ out)
{
    const int b   = blockIdx.x & 3;          // XCD swizzle (r12-proven)
    const int nt  = blockIdx.x >> 2;
    const int tid = threadIdx.x;
    const int wv  = tid >> 6;                // 0..7
    const int rg  = (wv >> 2) & 1;           // row-group (32 rows)
    const int cg  = (wv >> 1) & 1;           // c-half (128 ch)
    const int s   = wv & 1;                  // key-half (2048 keys)
    const int lane = tid & 63;
    const int c32 = lane & 31;
    const int hi  = lane >> 5;

    __shared__ alignas(16) char smem[66048];
    float* obuf = (float*)smem;              // 64KB combine buffer
    float* ml   = (float*)(smem + 65536);    // [rg][s][32]

    const unsigned short* ktb = kt + (size_t)b * NHW * NC8;
    const unsigned short* vtb = vt + (size_t)b * (NHW / 8) * NC * 8;

    const int nr0 = nt * 64 + rg * 32;
    const unsigned short* qp = qt + ((size_t)b * NHW + nr0 + c32) * NC8;
    const bf16x8 qf0 = *(const bf16x8*)(qp + hi * 8);        // d 0..15
    const bf16x8 qf1 = *(const bf16x8*)(qp + 16 + hi * 8);   // d 16..31

    f32x16 acc[4];
#pragma unroll
    for (int ct = 0; ct < 4; ++ct) acc[ct] = (f32x16)0.0f;
    float lrun = 0.f;
    const f32x16 zz = (f32x16)0.0f;

    int voff[8];
#pragma unroll
    for (int kc = 0; kc < 2; ++kc)
#pragma unroll
        for (int ct = 0; ct < 4; ++ct)
            voff[kc * 4 + ct] = (((kc * 2 + hi) * NC) + cg * 128 + ct * 32 + c32) * 8;

    const size_t VSTEP = (size_t)4 * NC * 8;     // one 32-key step of vt
    const size_t KSTEP = (size_t)32 * NC8;       // one 32-key step of kt

    const unsigned short* vApt = vtb + (size_t)(s * 256) * NC * 8;   // t even
    const unsigned short* vBpt = vApt + VSTEP;                        // t odd
    const unsigned short* kApt = ktb + (size_t)(s * 2048 + c32) * NC8 + hi * 8;
    const unsigned short* kBpt = kApt + KSTEP;

    auto loadV = [&](bf16x8* v, const unsigned short* p) {
#pragma unroll
        for (int i = 0; i < 8; ++i)
            v[i] = *(const bf16x8*)(p + voff[i]);
    };
    auto loadK = [&](bf16x8& ka, bf16x8& kb, const unsigned short* p) {
        ka = *(const bf16x8*)p;
        kb = *(const bf16x8*)(p + 16);
    };
    auto qkt_pack = [&](const bf16x8& kfa, const bf16x8& kfb, unsigned* w) {
        f32x16 e = __builtin_amdgcn_mfma_f32_32x32x16_bf16(kfa, qf0, zz, 0, 0, 0);
        e = __builtin_amdgcn_mfma_f32_32x32x16_bf16(kfb, qf1, e, 0, 0, 0);
        float ladd = 0.f;
#pragma unroll
        for (int q = 0; q < 8; ++q) {
            const float pa = ex2(e[2 * q]);
            const float pb = ex2(e[2 * q + 1]);
            ladd += pa + pb;
            w[q] = packbf2(pa, pb);
        }
        lrun += ladd;
    };
    auto pv = [&](const bf16x8* v, const unsigned* w) {
#pragma unroll
        for (int kc = 0; kc < 2; ++kc) {
            const unsigned q0 = w[kc * 4 + 0];
            const unsigned q1 = w[kc * 4 + 1];
            const unsigned q2 = w[kc * 4 + 2];
            const unsigned q3 = w[kc * 4 + 3];
            const unsigned q0x = (unsigned)__shfl_xor((int)q0, 32);
            const unsigned q1x = (unsigned)__shfl_xor((int)q1, 32);
            const unsigned q2x = (unsigned)__shfl_xor((int)q2, 32);
            const unsigned q3x = (unsigned)__shfl_xor((int)q3, 32);
            union { unsigned u[4]; bf16x8 vv; } pa;
            pa.u[0] = hi ? q2x : q0;
            pa.u[1] = hi ? q3x : q1;
            pa.u[2] = hi ? q2  : q0x;
            pa.u[3] = hi ? q3  : q1x;
#pragma unroll
            for (int ct = 0; ct < 4; ++ct)
                acc[ct] = __builtin_amdgcn_mfma_f32_32x32x16_bf16(pa.vv, v[kc * 4 + ct], acc[ct], 0, 0, 0);
        }
    };

    // ---- pipeline: V/K 2-deep, softmax two ahead (wA even / wB odd) ----
    bf16x8 vA[8], vB[8], kAa, kAb, kBa, kBb;
    unsigned wA[8], wB[8];

    loadV(vA, vApt); loadK(kAa, kAb, kApt);
    loadV(vB, vBpt); loadK(kBa, kBb, kBpt);
    qkt_pack(kAa, kAb, wA);                  // w(0)
    kApt += 2 * KSTEP; loadK(kAa, kAb, kApt);        // K(2)
    qkt_pack(kBa, kBb, wB);                  // w(1)
    kBpt += 2 * KSTEP; loadK(kBa, kBb, kBpt);        // K(3)

    for (int tt = 0; tt < 32; ++tt) {
        const int t = tt * 2;
        pv(vA, wA);                          // consume w(t), vA(t)
        if (t + 2 < 64) {
            qkt_pack(kAa, kAb, wA);          // produce w(t+2)
            vApt += 2 * VSTEP; loadV(vA, vApt);              // V(t+2)
            if (t + 4 < 64) { kApt += 2 * KSTEP; loadK(kAa, kAb, kApt); }  // K(t+4)
        }
        pv(vB, wB);                          // consume w(t+1), vB(t+1)
        if (t + 3 < 64) {
            qkt_pack(kBa, kBb, wB);          // produce w(t+3)
            vBpt += 2 * VSTEP; loadV(vB, vBpt);              // V(t+3)
            if (t + 5 < 64) { kBpt += 2 * KSTEP; loadK(kBa, kBb, kBpt); }  // K(t+5)
        }
    }

    // ---- 2-way s-combine ----
    lrun += __shfl_xor(lrun, 32);
    ml[(rg * 2 + s) * 32 + c32] = lrun;
    __syncthreads();
    const float L = ml[(rg * 2 + 0) * 32 + c32] + ml[(rg * 2 + 1) * 32 + c32];
    const float gil = gamma[0] / L;
    float il[16];
#pragma unroll
    for (int r = 0; r < 16; ++r)
        il[r] = __shfl(gil, (r & 3) + 8 * (r >> 2) + 4 * hi);

    if (s == 1) {
#pragma unroll
        for (int ct = 0; ct < 4; ++ct)
#pragma unroll
            for (int rq = 0; rq < 4; ++rq) {
                f32x4 v;
#pragma unroll
                for (int j = 0; j < 4; ++j) v[j] = acc[ct][rq * 4 + j];
                *(f32x4*)(obuf + ((((rg * 2 + cg) * 16 + ct * 4 + rq) * 64) + lane) * 4) = v;
            }
    }
    __syncthreads();
    if (s == 0) {
#pragma unroll
        for (int ct = 0; ct < 4; ++ct) {
            const int c = cg * 128 + ct * 32 + c32;
#pragma unroll
            for (int rq = 0; rq < 4; ++rq) {
                const f32x4 p = *(const f32x4*)(obuf + ((((rg * 2 + cg) * 16 + ct * 4 + rq) * 64) + lane) * 4);
                const int nglob = nt * 64 + rg * 32 + rq * 8 + hi * 4;
                const size_t o = ((size_t)b * NC + c) * NHW + nglob;
                const f32x4 xv = *(const f32x4*)(x + o);
                f32x4 res;
#pragma unroll
                for (int j = 0; j < 4; ++j) {
                    const float v = acc[ct][rq * 4 + j] + p[j];
                    res[j] = fmaf(v, il[rq * 4 + j], xv[j]);
                }
                *(f32x4*)(out + o) = res;
            }
        }
    }
}

extern "C" void kernel_launch(void* const* d_in, const int* in_sizes, int n_in,
                              void* d_out, int out_size, void* d_ws, size_t ws_size,
                              hipStream_t stream) {
    const float* x     = (const float*)d_in[0];
    const float* g     = (const float*)d_in[1];
    const float* qw    = (const float*)d_in[2];
    const float* qb    = (const float*)d_in[3];
    const float* kw    = (const float*)d_in[4];
    const float* kb    = (const float*)d_in[5];
    const float* vw    = (const float*)d_in[6];
    const float* vb    = (const float*)d_in[7];
    const float* gamma = (const float*)d_in[8];
    float* out = (float*)d_out;

    unsigned short* qt = (unsigned short*)d_ws;
    unsigned short* kt = qt + (size_t)NB * NHW * NC8;
    unsigned short* vt = kt + (size_t)NB * NHW * NC8;

    qk_proj<<<dim3(NB * (NHW / 64), 2), 512, 0, stream>>>(x, g, qw, qb, kw, kb, qt, kt);
    v_proj <<<1024, 256, 0, stream>>>(g, vw, vb, vt);
    attn   <<<NB * (NHW / 64), 512, 0, stream>>>(qt, kt, vt, x, gamma, out);
}